// Round 1
// 301.364 us; speedup vs baseline: 1.0057x; 1.0057x over previous
//
#include <hip/hip_runtime.h>

// B=32, T=512, D=512, L=2048. x:(B,T,D) f32, durations:(B,T) f32.
// d_out = aligned (B,L,D) f32  ||  attn (B,T,L) f32.
//
// attn column l = softmax_t of -0.2*(l-start_t)^2. Terms more than
// sqrt(smin^2+200) frames from l are < e^-40 of the max term (denom >= 1),
// i.e. < 4.3e-18 -> exact 0 in fp32 outputs and invisible in the denom.
// So: per-l band by binary search; banded denom; banded gather for aligned;
// dense attn write with literal zeros outside the band.
//
// R5: Phase B walks the wave's 16-l union band ONCE with fully-distinct
// per-lane row addresses (64 lanes x 16B = full coalescing).
// R6 (this round): __launch_bounds__(256,4) to pin 4 blocks/CU (grid is
// exactly 4*256CU; >128 VGPRs made a 768+256 two-wave schedule = ~1.4x
// stretch). VGPR diet in Phase B (negam hoisted to regs, d0+li instead of
// 8 fl constants). Phase C rewritten: float4 stores (1KB/wave-instr),
// band test via thrS[l]=smin^2+200 compare (== old [bt0,bt1) band),
// per-l params hoisted out of the t loop.

typedef float v4f __attribute__((ext_vector_type(4)));

static constexpr int Bc = 32;
static constexpr int Tc = 512;
static constexpr int Dc = 512;
static constexpr int Lc = 2048;
static constexpr int LT = 64;             // frames per block
static constexpr float SIGMA = 0.2f;
static constexpr float CUT2 = 200.0f;     // 40/SIGMA

// Kernel 1: starts[b][t] = exclusive cumsum of durations along t.
__global__ void cumsum_starts(const float* __restrict__ dur,
                              float* __restrict__ starts) {
  const int b = blockIdx.x;
  const int t = threadIdx.x; // blockDim.x == Tc
  __shared__ float buf[Tc];
  float d = dur[(size_t)b * Tc + t];
  float v = d;
  buf[t] = v;
  __syncthreads();
  for (int off = 1; off < Tc; off <<= 1) {
    float add = (t >= off) ? buf[t - off] : 0.0f;
    __syncthreads();
    v += add;
    buf[t] = v;
    __syncthreads();
  }
  starts[(size_t)b * Tc + t] = v - d;
}

// Kernel 2: one 256-thread block per (b, 64-frame tile).
__global__ void __launch_bounds__(256, 4)
soft_align(const float* __restrict__ x,
           const float* __restrict__ starts,
           float* __restrict__ aligned,
           float* __restrict__ attn) {
  const int tid = threadIdx.x;
  const int b = blockIdx.x >> 5;            // / (Lc/LT = 32)
  const int tile = blockIdx.x & 31;
  const int l0 = tile * LT;

  __shared__ float sbS[Tc];                 // token start offsets
  __shared__ __align__(16) float negamS[LT];// SIGMA*smin^2 per l
  __shared__ __align__(16) float invS[LT];  // 1/denom per l
  __shared__ __align__(16) float thrS[LT];  // smin^2 + 200 per l (band radius^2)
  __shared__ float dred[LT][4];             // denom partials
  __shared__ int bt0S[LT], bt1S[LT];        // per-l significant band
  __shared__ int T0w[4], T1w[4];            // per-wave union band

  if (tid < 4) { T0w[tid] = Tc; T1w[tid] = 0; }
  sbS[tid]       = starts[(size_t)b * Tc + tid];
  sbS[tid + 256] = starts[(size_t)b * Tc + tid + 256];
  __syncthreads();

  // Per-l: nearest start (exact softmax max) + band bounds, by binary search.
  if (tid < LT) {
    const float fl = (float)(l0 + tid);
    int lo = 0, hi = Tc;
    while (lo < hi) { int mid = (lo + hi) >> 1; if (sbS[mid] <= fl) lo = mid + 1; else hi = mid; }
    float smin = fl - sbS[lo - 1];          // sbS[0]=0 <= fl -> lo >= 1
    if (lo < Tc) smin = fminf(smin, sbS[lo] - fl);
    const float smin2 = smin * smin;
    negamS[tid] = SIGMA * smin2;
    thrS[tid] = smin2 + CUT2;
    const float smax = sqrtf(smin2 + CUT2);
    const float loV = fl - smax, hiV = fl + smax;
    // bt0 = first t with sbS[t] >= loV  (within [0, lo])
    int a = 0, c = lo;
    while (a < c) { int mid = (a + c) >> 1; if (sbS[mid] < loV) a = mid + 1; else c = mid; }
    const int bt0 = a;
    // bt1 = first t with sbS[t] > hiV   (within [lo, Tc])
    a = lo; c = Tc;
    while (a < c) { int mid = (a + c) >> 1; if (sbS[mid] <= hiV) a = mid + 1; else c = mid; }
    const int bt1 = a;                      // band nonempty (nearest inside)
    bt0S[tid] = bt0; bt1S[tid] = bt1;
    atomicMin(&T0w[tid >> 4], bt0);
    atomicMax(&T1w[tid >> 4], bt1);
  }
  __syncthreads();

  // Phase A: banded exact-in-fp32 denominators. 4 threads per l.
  {
    const int lg = tid >> 2, inner = tid & 3;
    const float fl = (float)(l0 + lg);
    const float negam = negamS[lg];
    float partial = 0.0f;
    const int e0 = bt0S[lg], e1 = bt1S[lg];
    for (int t = e0 + inner; t < e1; t += 4) {
      const float s = fl - sbS[t];
      partial += __expf(negam - SIGMA * s * s); // <= 1, max term = 1
    }
    dred[lg][inner] = partial;
  }
  __syncthreads();
  if (tid < LT) {
    invS[tid] = 1.0f / (dred[tid][0] + dred[tid][1] + dred[tid][2] + dred[tid][3]);
  }
  __syncthreads();

  // Phase B: aligned gather over the wave's union band, one pass.
  // Lane reads 2 distinct float4 of row t (full coalescing); 8 l per half.
  {
    const int w = tid >> 6;                 // wave id, covers l [16w,16w+16)
    const int lane = tid & 63;
    const int Tb0 = T0w[w], Tb1 = T1w[w];
    const float4* __restrict__ xb = (const float4*)(x + (size_t)b * Tc * Dc);
    for (int half = 0; half < 2; ++half) {
      const int lbase = 16 * w + 8 * half;
      float negam_r[8];
      #pragma unroll
      for (int li = 0; li < 8; ++li) negam_r[li] = negamS[lbase + li];
      const float flb = (float)(l0 + lbase);
      float4 acc[8][2] = {};
      for (int t = Tb0; t < Tb1; ++t) {
        const float4 r0 = xb[(size_t)t * (Dc / 4) + lane];
        const float4 r1 = xb[(size_t)t * (Dc / 4) + 64 + lane];
        const float d0 = flb - sbS[t];
        #pragma unroll
        for (int li = 0; li < 8; ++li) {
          const float s = d0 + (float)li;
          const float wgt = __expf(negam_r[li] - SIGMA * s * s);
          acc[li][0].x += wgt * r0.x; acc[li][0].y += wgt * r0.y;
          acc[li][0].z += wgt * r0.z; acc[li][0].w += wgt * r0.w;
          acc[li][1].x += wgt * r1.x; acc[li][1].y += wgt * r1.y;
          acc[li][1].z += wgt * r1.z; acc[li][1].w += wgt * r1.w;
        }
      }
      #pragma unroll
      for (int li = 0; li < 8; ++li) {
        const float inv = invS[lbase + li];
        v4f* __restrict__ ab =
            (v4f*)(aligned + ((size_t)b * Lc + l0 + lbase + li) * Dc);
        v4f v0 = { acc[li][0].x * inv, acc[li][0].y * inv,
                   acc[li][0].z * inv, acc[li][0].w * inv };
        v4f v1 = { acc[li][1].x * inv, acc[li][1].y * inv,
                   acc[li][1].z * inv, acc[li][1].w * inv };
        __builtin_nontemporal_store(v0, ab + lane);      // 1KB/instr, contiguous
        __builtin_nontemporal_store(v1, ab + 64 + lane);
      }
    }
  }

  // Phase C: dense attn write; literal zeros outside the per-l band.
  // Lane = (tSub, l4): wave stores 4 rows x 256B = 1KB per instruction.
  // In-band test: (l - sb[t])^2 <= smin^2+200  == the old [bt0,bt1) band.
  {
    const int w = tid >> 6;
    const int lane = tid & 63;
    const int tSub = lane >> 4;             // 0..3
    const int l4 = (lane & 15) * 4;         // 0,4,...,60
    const v4f ng = *(const v4f*)&negamS[l4];
    const v4f iv = *(const v4f*)&invS[l4];
    const v4f th = *(const v4f*)&thrS[l4];
    const float flb = (float)(l0 + l4);
    float* __restrict__ ap = attn + (size_t)b * Tc * Lc + l0 + l4;
    for (int p = 0; p < Tc / 16; ++p) {
      const int t = p * 16 + w * 4 + tSub;
      const float d0 = flb - sbS[t];
      v4f val;
      #pragma unroll
      for (int j = 0; j < 4; ++j) {
        const float s = d0 + (float)j;
        const float ss = s * s;
        val[j] = (ss <= th[j]) ? __expf(ng[j] - SIGMA * ss) * iv[j] : 0.0f;
      }
      __builtin_nontemporal_store(val, (v4f*)(ap + (size_t)t * Lc));
    }
  }
}

extern "C" void kernel_launch(void* const* d_in, const int* in_sizes, int n_in,
                              void* d_out, int out_size, void* d_ws, size_t ws_size,
                              hipStream_t stream) {
  const float* x   = (const float*)d_in[0];
  const float* dur = (const float*)d_in[1];

  float* aligned = (float*)d_out;                        // B*L*D
  float* attn    = (float*)d_out + (size_t)Bc * Lc * Dc; // B*T*L
  float* starts  = (float*)d_ws;                         // B*T

  cumsum_starts<<<Bc, Tc, 0, stream>>>(dur, starts);
  soft_align<<<Bc * (Lc / LT), 256, 0, stream>>>(x, starts, aligned, attn);
}

// Round 2
// 298.122 us; speedup vs baseline: 1.0166x; 1.0109x over previous
//
#include <hip/hip_runtime.h>

// B=32, T=512, D=512, L=2048. x:(B,T,D) f32, durations:(B,T) f32.
// d_out = aligned (B,L,D) f32  ||  attn (B,T,L) f32.
//
// attn column l = softmax_t of -0.2*(l-start_t)^2. Terms more than
// sqrt(smin^2+200) frames from l are < e^-40 of the max term (denom >= 1),
// i.e. < 4.3e-18 -> exact 0 in fp32 outputs and invisible in the denom.
// So: per-l band by binary search; banded denom; banded gather for aligned;
// dense attn write with literal zeros outside the band.
//
// R5: Phase B walks the wave's 16-l union band ONCE with fully-distinct
// per-lane row addresses (64 lanes x 16B = full coalescing).
// R6: __launch_bounds__(256,4); Phase B VGPR diet; Phase C float4 stores.
// R7 (this round):
//  - cumsum fused into soft_align (in-block shfl wave-scan of the 512
//    durations -> sbS directly). Removes the separate kernel + serial
//    launch gap + starts global round-trip. d_ws now unused.
//  - XCD-chunked block swizzle: swz=(bid&7)*128+(bid>>3) gives each XCD
//    4 consecutive b (4MB of x = its L2), so cross-tile row reuse hits L2
//    instead of re-fetching HBM. NT output stores keep L2 clean.

typedef float v4f __attribute__((ext_vector_type(4)));

static constexpr int Bc = 32;
static constexpr int Tc = 512;
static constexpr int Dc = 512;
static constexpr int Lc = 2048;
static constexpr int LT = 64;             // frames per block
static constexpr float SIGMA = 0.2f;
static constexpr float CUT2 = 200.0f;     // 40/SIGMA

// One 256-thread block per (b, 64-frame tile).
__global__ void __launch_bounds__(256, 4)
soft_align(const float* __restrict__ x,
           const float* __restrict__ dur,
           float* __restrict__ aligned,
           float* __restrict__ attn) {
  const int tid = threadIdx.x;
  const int bid = blockIdx.x;
  // XCD-chunked swizzle: 1024 blocks, 8 XCDs -> 128 logical tiles per XCD
  // (= 4 consecutive b). Bijective since 1024 % 8 == 0.
  const int swz = (bid & 7) * 128 + (bid >> 3);
  const int b = swz >> 5;                   // / (Lc/LT = 32)
  const int tile = swz & 31;
  const int l0 = tile * LT;

  __shared__ float sbS[Tc];                 // token start offsets
  __shared__ __align__(16) float negamS[LT];// SIGMA*smin^2 per l
  __shared__ __align__(16) float invS[LT];  // 1/denom per l
  __shared__ __align__(16) float thrS[LT];  // smin^2 + 200 per l (band radius^2)
  __shared__ float dred[LT][4];             // denom partials
  __shared__ int bt0S[LT], bt1S[LT];        // per-l significant band
  __shared__ int T0w[4], T1w[4];            // per-wave union band
  __shared__ float wsumS[4];                // per-wave duration sums (scan)

  // Fused exclusive cumsum of durations -> sbS.
  // Wave w scans elements [128w, 128w+128), 2 per lane, shfl_up scan.
  {
    const int w = tid >> 6, lane = tid & 63;
    const int e0 = 128 * w + 2 * lane;
    const float2 dv = *(const float2*)(dur + (size_t)b * Tc + e0);
    const float p = dv.x + dv.y;
    float s = p;
    #pragma unroll
    for (int off = 1; off < 64; off <<= 1) {
      const float v = __shfl_up(s, off);
      if (lane >= off) s += v;
    }
    if (lane == 63) wsumS[w] = s;
    if (tid < 4) { T0w[tid] = Tc; T1w[tid] = 0; }
    __syncthreads();
    float prefix = 0.0f;
    #pragma unroll
    for (int i = 0; i < 3; ++i) prefix += (i < w) ? wsumS[i] : 0.0f;
    sbS[e0]     = prefix + s - p;            // excl. prefix of e0
    sbS[e0 + 1] = prefix + s - dv.y;         // excl. prefix of e0+1
  }
  __syncthreads();

  // Per-l: nearest start (exact softmax max) + band bounds, by binary search.
  if (tid < LT) {
    const float fl = (float)(l0 + tid);
    int lo = 0, hi = Tc;
    while (lo < hi) { int mid = (lo + hi) >> 1; if (sbS[mid] <= fl) lo = mid + 1; else hi = mid; }
    float smin = fl - sbS[lo - 1];          // sbS[0]=0 <= fl -> lo >= 1
    if (lo < Tc) smin = fminf(smin, sbS[lo] - fl);
    const float smin2 = smin * smin;
    negamS[tid] = SIGMA * smin2;
    thrS[tid] = smin2 + CUT2;
    const float smax = sqrtf(smin2 + CUT2);
    const float loV = fl - smax, hiV = fl + smax;
    // bt0 = first t with sbS[t] >= loV  (within [0, lo])
    int a = 0, c = lo;
    while (a < c) { int mid = (a + c) >> 1; if (sbS[mid] < loV) a = mid + 1; else c = mid; }
    const int bt0 = a;
    // bt1 = first t with sbS[t] > hiV   (within [lo, Tc])
    a = lo; c = Tc;
    while (a < c) { int mid = (a + c) >> 1; if (sbS[mid] <= hiV) a = mid + 1; else c = mid; }
    const int bt1 = a;                      // band nonempty (nearest inside)
    bt0S[tid] = bt0; bt1S[tid] = bt1;
    atomicMin(&T0w[tid >> 4], bt0);
    atomicMax(&T1w[tid >> 4], bt1);
  }
  __syncthreads();

  // Phase A: banded exact-in-fp32 denominators. 4 threads per l.
  {
    const int lg = tid >> 2, inner = tid & 3;
    const float fl = (float)(l0 + lg);
    const float negam = negamS[lg];
    float partial = 0.0f;
    const int e0 = bt0S[lg], e1 = bt1S[lg];
    for (int t = e0 + inner; t < e1; t += 4) {
      const float s = fl - sbS[t];
      partial += __expf(negam - SIGMA * s * s); // <= 1, max term = 1
    }
    dred[lg][inner] = partial;
  }
  __syncthreads();
  if (tid < LT) {
    invS[tid] = 1.0f / (dred[tid][0] + dred[tid][1] + dred[tid][2] + dred[tid][3]);
  }
  __syncthreads();

  // Phase B: aligned gather over the wave's union band, one pass per half.
  // Lane reads 2 distinct float4 of row t (full coalescing); 8 l per half.
  {
    const int w = tid >> 6;                 // wave id, covers l [16w,16w+16)
    const int lane = tid & 63;
    const int Tb0 = T0w[w], Tb1 = T1w[w];
    const float4* __restrict__ xb = (const float4*)(x + (size_t)b * Tc * Dc);
    for (int half = 0; half < 2; ++half) {
      const int lbase = 16 * w + 8 * half;
      float negam_r[8];
      #pragma unroll
      for (int li = 0; li < 8; ++li) negam_r[li] = negamS[lbase + li];
      const float flb = (float)(l0 + lbase);
      float4 acc[8][2] = {};
      for (int t = Tb0; t < Tb1; ++t) {
        const float4 r0 = xb[(size_t)t * (Dc / 4) + lane];
        const float4 r1 = xb[(size_t)t * (Dc / 4) + 64 + lane];
        const float d0 = flb - sbS[t];
        #pragma unroll
        for (int li = 0; li < 8; ++li) {
          const float s = d0 + (float)li;
          const float wgt = __expf(negam_r[li] - SIGMA * s * s);
          acc[li][0].x += wgt * r0.x; acc[li][0].y += wgt * r0.y;
          acc[li][0].z += wgt * r0.z; acc[li][0].w += wgt * r0.w;
          acc[li][1].x += wgt * r1.x; acc[li][1].y += wgt * r1.y;
          acc[li][1].z += wgt * r1.z; acc[li][1].w += wgt * r1.w;
        }
      }
      #pragma unroll
      for (int li = 0; li < 8; ++li) {
        const float inv = invS[lbase + li];
        v4f* __restrict__ ab =
            (v4f*)(aligned + ((size_t)b * Lc + l0 + lbase + li) * Dc);
        v4f v0 = { acc[li][0].x * inv, acc[li][0].y * inv,
                   acc[li][0].z * inv, acc[li][0].w * inv };
        v4f v1 = { acc[li][1].x * inv, acc[li][1].y * inv,
                   acc[li][1].z * inv, acc[li][1].w * inv };
        __builtin_nontemporal_store(v0, ab + lane);      // 1KB/instr, contiguous
        __builtin_nontemporal_store(v1, ab + 64 + lane);
      }
    }
  }

  // Phase C: dense attn write; literal zeros outside the per-l band.
  // Lane = (tSub, l4): wave stores 4 rows x 256B = 1KB per instruction.
  // In-band test: (l - sb[t])^2 <= smin^2+200  == the old [bt0,bt1) band.
  {
    const int w = tid >> 6;
    const int lane = tid & 63;
    const int tSub = lane >> 4;             // 0..3
    const int l4 = (lane & 15) * 4;         // 0,4,...,60
    const v4f ng = *(const v4f*)&negamS[l4];
    const v4f iv = *(const v4f*)&invS[l4];
    const v4f th = *(const v4f*)&thrS[l4];
    const float flb = (float)(l0 + l4);
    float* __restrict__ ap = attn + (size_t)b * Tc * Lc + l0 + l4;
    for (int p = 0; p < Tc / 16; ++p) {
      const int t = p * 16 + w * 4 + tSub;
      const float d0 = flb - sbS[t];
      v4f val;
      #pragma unroll
      for (int j = 0; j < 4; ++j) {
        const float s = d0 + (float)j;
        const float ss = s * s;
        val[j] = (ss <= th[j]) ? __expf(ng[j] - SIGMA * ss) * iv[j] : 0.0f;
      }
      __builtin_nontemporal_store(val, (v4f*)(ap + (size_t)t * Lc));
    }
  }
}

extern "C" void kernel_launch(void* const* d_in, const int* in_sizes, int n_in,
                              void* d_out, int out_size, void* d_ws, size_t ws_size,
                              hipStream_t stream) {
  const float* x   = (const float*)d_in[0];
  const float* dur = (const float*)d_in[1];

  float* aligned = (float*)d_out;                        // B*L*D
  float* attn    = (float*)d_out + (size_t)Bc * Lc * Dc; // B*T*L

  soft_align<<<Bc * (Lc / LT), 256, 0, stream>>>(x, dur, aligned, attn);
}